// Round 1
// baseline (874.445 us; speedup 1.0000x reference)
//
#include <hip/hip_runtime.h>
#include <cstdint>
#include <cstddef>

typedef __bf16 bf16_t;
typedef __bf16 bf16x8 __attribute__((ext_vector_type(8)));
typedef float f32x4_t __attribute__((ext_vector_type(4)));

#define DEVI static __device__ __forceinline__

DEVI f32x4_t mfma_16x16x32_bf16(bf16x8 a, bf16x8 b, f32x4_t c) {
  return __builtin_amdgcn_mfma_f32_16x16x32_bf16(a, b, c, 0, 0, 0);
}

// ---------------------------------------------------------------------------
// Weight transpose: [512][512] f32 row-major (k,n) -> bf16 [n][512] (k-contig)
// ---------------------------------------------------------------------------
__global__ void k_wtrans(const float* __restrict__ wq, const float* __restrict__ wk,
                         const float* __restrict__ wv, const float* __restrict__ wo,
                         bf16_t* __restrict__ wt_qkv, bf16_t* __restrict__ wt_o) {
  __shared__ float tile[64][65];
  const int mat = blockIdx.z;
  const float* src = (mat == 0) ? wq : (mat == 1) ? wk : (mat == 2) ? wv : wo;
  bf16_t* dst = (mat == 3) ? wt_o : (wt_qkv + (size_t)mat * 512 * 512);
  const int n0 = blockIdx.x * 64, k0 = blockIdx.y * 64;
  const int t = threadIdx.x;
  {
    const int k = t >> 2, cs = t & 3;
    const float4* s4 = (const float4*)(src + (size_t)(k0 + k) * 512 + n0 + cs * 16);
#pragma unroll
    for (int i = 0; i < 4; ++i) {
      float4 v = s4[i];
      tile[k][cs * 16 + i * 4 + 0] = v.x;
      tile[k][cs * 16 + i * 4 + 1] = v.y;
      tile[k][cs * 16 + i * 4 + 2] = v.z;
      tile[k][cs * 16 + i * 4 + 3] = v.w;
    }
  }
  __syncthreads();
  {
    const int n = t >> 2, cs = t & 3;
    __align__(16) bf16_t vals[16];
#pragma unroll
    for (int i = 0; i < 16; ++i) vals[i] = (bf16_t)tile[cs * 16 + i][n];
    bf16_t* d = dst + (size_t)(n0 + n) * 512 + k0 + cs * 16;
    ((int4*)d)[0] = ((int4*)vals)[0];
    ((int4*)d)[1] = ((int4*)vals)[1];
  }
}

// ---------------------------------------------------------------------------
// Fused QKV projection GEMM: C[8192 x 1536] = A[8192 x 512] * W + bias
// A = queries (n<512) or keys_values (n>=512). Output scattered to (b,h,n,64).
// ---------------------------------------------------------------------------
__global__ __launch_bounds__(256) void k_proj(
    const float* __restrict__ queries, const float* __restrict__ kv,
    const bf16_t* __restrict__ wt, const float* __restrict__ bq,
    const float* __restrict__ bk, const float* __restrict__ bv,
    bf16_t* __restrict__ Qb, bf16_t* __restrict__ Kb, bf16_t* __restrict__ Vb) {
  __shared__ __align__(16) bf16_t al[128 * 72];  // +8 pad: stride 144B, 16B aligned
  __shared__ __align__(16) bf16_t bl[128 * 72];
  const int bm = blockIdx.x, bn = blockIdx.y;
  const int proj = bn >> 2;  // 0=Q,1=K,2=V (4 n-blocks of 128 each)
  const float* A = (proj == 0) ? queries : kv;
  const int t = threadIdx.x, lane = t & 63, w = t >> 6;
  const int g = lane >> 4, c15 = lane & 15;
  const int wm = w >> 1, wn = w & 1;
  f32x4_t acc[4][4] = {};
  for (int kt = 0; kt < 8; ++kt) {
    __syncthreads();
    {
      const int row = t >> 1, half = t & 1;
      const float4* s4 = (const float4*)(A + (size_t)(bm * 128 + row) * 512 + kt * 64 + half * 32);
      bf16_t* da = &al[row * 72 + half * 32];
#pragma unroll
      for (int i = 0; i < 8; ++i) {
        float4 v = s4[i];
        __align__(8) bf16_t u[4] = {(bf16_t)v.x, (bf16_t)v.y, (bf16_t)v.z, (bf16_t)v.w};
        *(int2*)(da + i * 4) = *(int2*)u;
      }
      const int4* sb = (const int4*)(wt + (size_t)(bn * 128 + row) * 512 + kt * 64 + half * 32);
      int4* db = (int4*)&bl[row * 72 + half * 32];
#pragma unroll
      for (int i = 0; i < 4; ++i) db[i] = sb[i];
    }
    __syncthreads();
#pragma unroll
    for (int c = 0; c < 2; ++c) {
      bf16x8 af[4], bfv[4];
#pragma unroll
      for (int mi = 0; mi < 4; ++mi)
        af[mi] = *(const bf16x8*)&al[(wm * 64 + mi * 16 + c15) * 72 + c * 32 + g * 8];
#pragma unroll
      for (int ni = 0; ni < 4; ++ni)
        bfv[ni] = *(const bf16x8*)&bl[(wn * 64 + ni * 16 + c15) * 72 + c * 32 + g * 8];
#pragma unroll
      for (int mi = 0; mi < 4; ++mi)
#pragma unroll
        for (int ni = 0; ni < 4; ++ni)
          acc[mi][ni] = mfma_16x16x32_bf16(af[mi], bfv[ni], acc[mi][ni]);
    }
  }
  const float* bias = (proj == 0) ? bq : (proj == 1) ? bk : bv;
  bf16_t* outp = (proj == 0) ? Qb : (proj == 1) ? Kb : Vb;
#pragma unroll
  for (int ni = 0; ni < 4; ++ni) {
    const int ng = bn * 128 + wn * 64 + ni * 16 + c15;
    const int nl = ng & 511;
    const int h = nl >> 6, d = nl & 63;
    const float bi = bias[nl];
#pragma unroll
    for (int mi = 0; mi < 4; ++mi)
#pragma unroll
      for (int r = 0; r < 4; ++r) {
        const int m = bm * 128 + wm * 64 + mi * 16 + g * 4 + r;
        const int b_ = m >> 11, pos = m & 2047;
        outp[((size_t)((b_ * 8 + h) * 2048 + pos) << 6) + d] = (bf16_t)(acc[mi][ni][r] + bi);
      }
  }
}

// ---------------------------------------------------------------------------
// V (b,h,2048,64) -> Vt (b,h,64,2048)
// ---------------------------------------------------------------------------
__global__ void k_vtrans(const bf16_t* __restrict__ V, bf16_t* __restrict__ Vt) {
  __shared__ __align__(16) bf16_t tile[64 * 72];
  const int bh = blockIdx.x, kt = blockIdx.y, t = threadIdx.x;
  const int row = t >> 3, c = t & 7;
#pragma unroll
  for (int p = 0; p < 2; ++p) {
    const int r = p * 32 + row;
    *(int4*)&tile[r * 72 + c * 8] =
        *(const int4*)(V + ((size_t)(bh * 2048 + kt * 64 + r) << 6) + c * 8);
  }
  __syncthreads();
#pragma unroll
  for (int p = 0; p < 2; ++p) {
    const int dv = p * 32 + row;
    __align__(16) bf16_t vals[8];
#pragma unroll
    for (int j = 0; j < 8; ++j) vals[j] = tile[(c * 8 + j) * 72 + dv];
    *(int4*)(Vt + ((size_t)bh << 17) + (size_t)dv * 2048 + kt * 64 + c * 8) = *(int4*)vals;
  }
}

// ---------------------------------------------------------------------------
// Flash attention with multiplicative pre-softmax weights.
// grid (bh=32, qtile=32): blockid%8 == h -> each head pinned to one XCD (K/V L2 reuse).
// 4 waves, each owns 16 q-rows. KBLK=64, K/V double-buffered, W prefetched 1 tile ahead.
// ---------------------------------------------------------------------------
__global__ __launch_bounds__(256, 3) void k_attn(
    const bf16_t* __restrict__ Qb, const bf16_t* __restrict__ Kb,
    const bf16_t* __restrict__ Vtb, const float* __restrict__ attw,
    bf16_t* __restrict__ AOb) {
  __shared__ __align__(16) bf16_t kbuf[2][64 * 72];
  __shared__ __align__(16) bf16_t vbuf[2][64 * 72];
  __shared__ __align__(16) bf16_t qp[64 * 72];  // Q staging, then P tile
  const int bh = blockIdx.x, qt = blockIdx.y;
  const int b = bh >> 3, h = bh & 7;
  const int t = threadIdx.x, lane = t & 63, w = t >> 6;
  const int g = lane >> 4, c15 = lane & 15;
  const int q0 = qt * 64;
  const bf16_t* Qp = Qb + ((size_t)(bh * 2048 + q0) << 6);
  const bf16_t* Kp = Kb + ((size_t)bh << 17);
  const bf16_t* Vp = Vtb + ((size_t)bh << 17);
  const float* Wp = attw + (size_t)(bh * 2048 + q0) * 2048;
  const int srow = t >> 3, sc8 = t & 7;
  // prologue: stage Q + K0 + V0
#pragma unroll
  for (int p = 0; p < 2; ++p) {
    const int r = p * 32 + srow;
    *(int4*)&qp[r * 72 + sc8 * 8] = *(const int4*)(Qp + ((size_t)r << 6) + sc8 * 8);
    *(int4*)&kbuf[0][r * 72 + sc8 * 8] = *(const int4*)(Kp + ((size_t)r << 6) + sc8 * 8);
    *(int4*)&vbuf[0][r * 72 + sc8 * 8] = *(const int4*)(Vp + (size_t)r * 2048 + sc8 * 8);
  }
  __syncthreads();
  bf16x8 qa0 = *(const bf16x8*)&qp[(w * 16 + c15) * 72 + g * 8];
  bf16x8 qa1 = *(const bf16x8*)&qp[(w * 16 + c15) * 72 + 32 + g * 8];
  __syncthreads();  // all waves have Q frags; qp becomes the P buffer
  const float* wlane = Wp + (size_t)(w * 16 + g * 4) * 2048 + c15;
  float wreg[16];
#pragma unroll
  for (int tt = 0; tt < 4; ++tt)
#pragma unroll
    for (int r = 0; r < 4; ++r) wreg[tt * 4 + r] = wlane[(size_t)r * 2048 + tt * 16];
  f32x4_t o[4] = {};
  float m_[4] = {-3e38f, -3e38f, -3e38f, -3e38f};
  float l_[4] = {0.f, 0.f, 0.f, 0.f};
  for (int kt = 0; kt < 32; ++kt) {
    const int cur = kt & 1, nxt = cur ^ 1;
    const bool pf = (kt < 31);
    float wnx[16];
    int4 kst[2], vst[2];
    if (pf) {  // prefetch next W tile + next K/V tiles into registers
#pragma unroll
      for (int tt = 0; tt < 4; ++tt)
#pragma unroll
        for (int r = 0; r < 4; ++r)
          wnx[tt * 4 + r] = wlane[(size_t)r * 2048 + (kt + 1) * 64 + tt * 16];
#pragma unroll
      for (int p = 0; p < 2; ++p) {
        const int r = p * 32 + srow;
        kst[p] = *(const int4*)(Kp + ((size_t)((kt + 1) * 64 + r) << 6) + sc8 * 8);
        vst[p] = *(const int4*)(Vp + (size_t)r * 2048 + (kt + 1) * 64 + sc8 * 8);
      }
    }
    // S = Q K^T  (16 q-rows x 64 keys per wave)
    f32x4_t s[4] = {};
#pragma unroll
    for (int tt = 0; tt < 4; ++tt)
#pragma unroll
      for (int c = 0; c < 2; ++c) {
        bf16x8 kb = *(const bf16x8*)&kbuf[cur][(tt * 16 + c15) * 72 + c * 32 + g * 8];
        s[tt] = mfma_16x16x32_bf16((c == 0) ? qa0 : qa1, kb, s[tt]);
      }
    // scale * W, online softmax (rows live in 16-lane groups)
    float p_[4][4];
#pragma unroll
    for (int r = 0; r < 4; ++r) {
#pragma unroll
      for (int tt = 0; tt < 4; ++tt) p_[tt][r] = s[tt][r] * 0.125f * wreg[tt * 4 + r];
      float x = fmaxf(fmaxf(p_[0][r], p_[1][r]), fmaxf(p_[2][r], p_[3][r]));
      x = fmaxf(x, __shfl_xor(x, 1));
      x = fmaxf(x, __shfl_xor(x, 2));
      x = fmaxf(x, __shfl_xor(x, 4));
      x = fmaxf(x, __shfl_xor(x, 8));
      const float mn = fmaxf(m_[r], x);
      const float sc = exp2f((m_[r] - mn) * 1.44269504f);
      float ps = 0.f;
#pragma unroll
      for (int tt = 0; tt < 4; ++tt) {
        const float e = exp2f((p_[tt][r] - mn) * 1.44269504f);
        p_[tt][r] = e;
        ps += e;
      }
      ps += __shfl_xor(ps, 1);
      ps += __shfl_xor(ps, 2);
      ps += __shfl_xor(ps, 4);
      ps += __shfl_xor(ps, 8);
      l_[r] = l_[r] * sc + ps;
      m_[r] = mn;
#pragma unroll
      for (int tt = 0; tt < 4; ++tt) o[tt][r] *= sc;
    }
    // P -> LDS (wave-private rows), back as A-fragments
#pragma unroll
    for (int tt = 0; tt < 4; ++tt)
#pragma unroll
      for (int r = 0; r < 4; ++r)
        qp[(w * 16 + g * 4 + r) * 72 + tt * 16 + c15] = (bf16_t)p_[tt][r];
    asm volatile("s_waitcnt lgkmcnt(0)" ::: "memory");
    __builtin_amdgcn_sched_barrier(0);
    bf16x8 pa0 = *(const bf16x8*)&qp[(w * 16 + c15) * 72 + g * 8];
    bf16x8 pa1 = *(const bf16x8*)&qp[(w * 16 + c15) * 72 + 32 + g * 8];
#pragma unroll
    for (int tt = 0; tt < 4; ++tt) {
      bf16x8 vb0 = *(const bf16x8*)&vbuf[cur][(tt * 16 + c15) * 72 + g * 8];
      bf16x8 vb1 = *(const bf16x8*)&vbuf[cur][(tt * 16 + c15) * 72 + 32 + g * 8];
      o[tt] = mfma_16x16x32_bf16(pa0, vb0, o[tt]);
      o[tt] = mfma_16x16x32_bf16(pa1, vb1, o[tt]);
    }
    if (pf) {  // write prefetched K/V into the other buffer
#pragma unroll
      for (int p = 0; p < 2; ++p) {
        const int r = p * 32 + srow;
        *(int4*)&kbuf[nxt][r * 72 + sc8 * 8] = kst[p];
        *(int4*)&vbuf[nxt][r * 72 + sc8 * 8] = vst[p];
      }
#pragma unroll
      for (int i = 0; i < 16; ++i) wreg[i] = wnx[i];
    }
    __syncthreads();
  }
  // epilogue: normalize + store (b, q, h*64+dv) bf16
#pragma unroll
  for (int r = 0; r < 4; ++r) {
    const float inv = 1.f / l_[r];
    const int q = q0 + w * 16 + g * 4 + r;
    bf16_t* dst = AOb + ((size_t)(b * 2048 + q) << 9) + h * 64;
#pragma unroll
    for (int tt = 0; tt < 4; ++tt) dst[tt * 16 + c15] = (bf16_t)(o[tt][r] * inv);
  }
}

// ---------------------------------------------------------------------------
// Output projection + bias + residual: X[8192x512] = AO*Wo + bo + queries (f32)
// ---------------------------------------------------------------------------
__global__ __launch_bounds__(256) void k_ogemm(
    const bf16_t* __restrict__ Ab, const bf16_t* __restrict__ wto,
    const float* __restrict__ bo, const float* __restrict__ queries,
    float* __restrict__ X) {
  __shared__ __align__(16) bf16_t al[128 * 72];
  __shared__ __align__(16) bf16_t bl[128 * 72];
  const int bm = blockIdx.x, bn = blockIdx.y;
  const int t = threadIdx.x, lane = t & 63, w = t >> 6;
  const int g = lane >> 4, c15 = lane & 15;
  const int wm = w >> 1, wn = w & 1;
  f32x4_t acc[4][4] = {};
  for (int kt = 0; kt < 8; ++kt) {
    __syncthreads();
    {
      const int row = t >> 1, half = t & 1;
      const int4* sa = (const int4*)(Ab + (size_t)(bm * 128 + row) * 512 + kt * 64 + half * 32);
      int4* da = (int4*)&al[row * 72 + half * 32];
      const int4* sb = (const int4*)(wto + (size_t)(bn * 128 + row) * 512 + kt * 64 + half * 32);
      int4* db = (int4*)&bl[row * 72 + half * 32];
#pragma unroll
      for (int i = 0; i < 4; ++i) {
        da[i] = sa[i];
        db[i] = sb[i];
      }
    }
    __syncthreads();
#pragma unroll
    for (int c = 0; c < 2; ++c) {
      bf16x8 af[4], bfv[4];
#pragma unroll
      for (int mi = 0; mi < 4; ++mi)
        af[mi] = *(const bf16x8*)&al[(wm * 64 + mi * 16 + c15) * 72 + c * 32 + g * 8];
#pragma unroll
      for (int ni = 0; ni < 4; ++ni)
        bfv[ni] = *(const bf16x8*)&bl[(wn * 64 + ni * 16 + c15) * 72 + c * 32 + g * 8];
#pragma unroll
      for (int mi = 0; mi < 4; ++mi)
#pragma unroll
        for (int ni = 0; ni < 4; ++ni)
          acc[mi][ni] = mfma_16x16x32_bf16(af[mi], bfv[ni], acc[mi][ni]);
    }
  }
#pragma unroll
  for (int ni = 0; ni < 4; ++ni) {
    const int n = bn * 128 + wn * 64 + ni * 16 + c15;
    const float bi = bo[n];
#pragma unroll
    for (int mi = 0; mi < 4; ++mi)
#pragma unroll
      for (int r = 0; r < 4; ++r) {
        const int m = bm * 128 + wm * 64 + mi * 16 + g * 4 + r;
        X[(size_t)m * 512 + n] = acc[mi][ni][r] + bi + queries[(size_t)m * 512 + n];
      }
  }
}

// ---------------------------------------------------------------------------
// LayerNorm over 512, one wave per row
// ---------------------------------------------------------------------------
__global__ void k_ln(const float* __restrict__ X, const float* __restrict__ gam,
                     const float* __restrict__ bet, float* __restrict__ out) {
  const int t = threadIdx.x, lane = t & 63, w = t >> 6;
  const int row = blockIdx.x * 4 + w;
  const float* xr = X + (size_t)row * 512 + lane * 8;
  float4 a = ((const float4*)xr)[0];
  float4 c = ((const float4*)xr)[1];
  float s = a.x + a.y + a.z + a.w + c.x + c.y + c.z + c.w;
  float sq = a.x * a.x + a.y * a.y + a.z * a.z + a.w * a.w +
             c.x * c.x + c.y * c.y + c.z * c.z + c.w * c.w;
#pragma unroll
  for (int msk = 1; msk < 64; msk <<= 1) {
    s += __shfl_xor(s, msk);
    sq += __shfl_xor(sq, msk);
  }
  const float mu = s * (1.f / 512.f);
  const float var = sq * (1.f / 512.f) - mu * mu;
  const float rs = rsqrtf(var + 1e-5f);
  const float4 g0 = ((const float4*)(gam + lane * 8))[0];
  const float4 g1 = ((const float4*)(gam + lane * 8))[1];
  const float4 b0 = ((const float4*)(bet + lane * 8))[0];
  const float4 b1 = ((const float4*)(bet + lane * 8))[1];
  float4 o0, o1;
  o0.x = (a.x - mu) * rs * g0.x + b0.x;
  o0.y = (a.y - mu) * rs * g0.y + b0.y;
  o0.z = (a.z - mu) * rs * g0.z + b0.z;
  o0.w = (a.w - mu) * rs * g0.w + b0.w;
  o1.x = (c.x - mu) * rs * g1.x + b1.x;
  o1.y = (c.y - mu) * rs * g1.y + b1.y;
  o1.z = (c.z - mu) * rs * g1.z + b1.z;
  o1.w = (c.w - mu) * rs * g1.w + b1.w;
  float* orow = out + (size_t)row * 512 + lane * 8;
  ((float4*)orow)[0] = o0;
  ((float4*)orow)[1] = o1;
}

// ---------------------------------------------------------------------------
extern "C" void kernel_launch(void* const* d_in, const int* in_sizes, int n_in,
                              void* d_out, int out_size, void* d_ws, size_t ws_size,
                              hipStream_t stream) {
  (void)in_sizes; (void)n_in; (void)out_size; (void)ws_size;
  const float* queries = (const float*)d_in[0];
  const float* keys_values = (const float*)d_in[1];
  const float* attw = (const float*)d_in[2];
  const float* Wq = (const float*)d_in[3];
  const float* bq = (const float*)d_in[4];
  const float* Wk = (const float*)d_in[5];
  const float* bk = (const float*)d_in[6];
  const float* Wv = (const float*)d_in[7];
  const float* bv = (const float*)d_in[8];
  const float* Wo = (const float*)d_in[9];
  const float* bo = (const float*)d_in[10];
  const float* lng = (const float*)d_in[11];
  const float* lnb = (const float*)d_in[12];
  float* out = (float*)d_out;
  char* ws = (char*)d_ws;
  bf16_t* wt_qkv = (bf16_t*)(ws + 0);         // 1536*512*2  = 1572864
  bf16_t* wt_o   = (bf16_t*)(ws + 1572864);   //  512*512*2  =  524288
  bf16_t* Qb     = (bf16_t*)(ws + 2097152);   // 32*2048*64*2 = 8388608
  bf16_t* Kb     = (bf16_t*)(ws + 10485760);
  bf16_t* Vb     = (bf16_t*)(ws + 18874368);
  bf16_t* Vt     = (bf16_t*)(ws + 27262976);
  bf16_t* AOb    = (bf16_t*)(ws + 35651584);
  float*  X      = (float*)(ws + 44040192);   // 8192*512*4 = 16777216 (end 60817408)

  k_wtrans<<<dim3(8, 8, 4), dim3(256), 0, stream>>>(Wq, Wk, Wv, Wo, wt_qkv, wt_o);
  k_proj<<<dim3(64, 12), dim3(256), 0, stream>>>(queries, keys_values, wt_qkv,
                                                 bq, bk, bv, Qb, Kb, Vb);
  k_vtrans<<<dim3(32, 32), dim3(256), 0, stream>>>(Vb, Vt);
  k_attn<<<dim3(32, 32), dim3(256), 0, stream>>>(Qb, Kb, Vt, attw, AOb);
  k_ogemm<<<dim3(64, 4), dim3(256), 0, stream>>>(AOb, wt_o, bo, queries, X);
  k_ln<<<dim3(2048), dim3(256), 0, stream>>>(X, lng, lnb, out);
}